// Round 7
// baseline (863.766 us; speedup 1.0000x reference)
//
#include <hip/hip_runtime.h>

#define NV 1448
#define JD 4344            // 3*NV
#define CC 256
#define BB 64
#define QQ 128             // 2*BB
#define NBLK 256
#define TPB 256
#define HALFR 724          // rows per chamfer block (NV/2)
#define JQN 1086           // JD/4 j-quads
#define NOCT 18            // max 8-q octs after per-side padding
#define NWARP (17 * NOCT)  // decode warps: 17 jw-slots x 18 octs = 306

struct Smem {
    union {
        struct {
            float Bx[1456], By[1456], Bz[1456], Bw[1456];  // padded cols (pad w=+inf)
            float Lmin[4][HALFR];                           // per-wave row-min merge
        } c;
    } u;
    float wred[4];
};

__device__ __forceinline__ void grid_barrier(unsigned* cnt, unsigned target) {
    __syncthreads();
    if (threadIdx.x == 0) {
        __threadfence();
        __hip_atomic_fetch_add(cnt, 1u, __ATOMIC_SEQ_CST, __HIP_MEMORY_SCOPE_AGENT);
        while (__hip_atomic_load(cnt, __ATOMIC_SEQ_CST, __HIP_MEMORY_SCOPE_AGENT) < target) {
            __builtin_amdgcn_s_sleep(2);
        }
        __threadfence();
    }
    __syncthreads();
}

__global__ __launch_bounds__(TPB) void fused_kernel(
        const float* __restrict__ inp, const float* __restrict__ tgt,
        const int* __restrict__ labels,
        const float* __restrict__ muL, const float* __restrict__ deltaL,
        const float* __restrict__ muR, const float* __restrict__ deltaR,
        unsigned* cnt, float* latQ, int* qperm, int* octside,
        float* pts3, float* partials, float* out)
{
    const int bid = blockIdx.x, tid = threadIdx.x;
    __shared__ Smem sm;

    // ---------------- P0: pool -> latQ[q][c]; build label-sorted qperm ----------------
    for (int p = 0; p < 8; ++p) {
        int gid = p * (NBLK * TPB) + bid * TPB + tid;   // 524288 = 32768 rows x 16 lanes
        int lane16 = gid & 15;
        int row = gid >> 4;
        int t = row >> 14;
        int bc = row & 16383;
        const float* src = (t ? tgt : inp) + (size_t)bc * 64;
        float4 v = reinterpret_cast<const float4*>(src)[lane16];
        float s = (v.x + v.y) + (v.z + v.w);
        s += __shfl_xor(s, 1);
        s += __shfl_xor(s, 2);
        s += __shfl_xor(s, 4);
        s += __shfl_xor(s, 8);
        if (lane16 == 0) {
            int b = bc >> 8, c = bc & 255;
            latQ[(size_t)(t * 64 + b) * CC + c] = s * (1.0f / 64.0f);
        }
    }
    if (bid == 0 && tid == 0) {
        int pos = 0;
        for (int side = 0; side < 2; ++side) {
            int start = pos;
            for (int t = 0; t < 2; ++t)
                for (int b = 0; b < BB; ++b)
                    if (labels[b] == side) qperm[pos++] = t * 64 + b;
            while (pos & 7) qperm[pos++] = -1;
            for (int o = (start >> 3); o < (pos >> 3); ++o) octside[o] = side;
        }
        for (int o = (pos >> 3); o < NOCT; ++o) octside[o] = -1;
        for (int i = pos; i < NOCT * 8; ++i) qperm[i] = -1;
    }
    grid_barrier(cnt, NBLK);

    // ---------------- P1: decode (LDS-free). warp W -> (oct, jw). ----------------
    {
        const int W = bid * 4 + (tid >> 6);
        const int lane = tid & 63;
        if (W < NWARP) {
            const int oct = W % NOCT;
            const int jw  = W / NOCT;             // 0..16
            const int side = octside[oct];
            if (side >= 0) {
                const int jq = jw * 64 + lane;
                const bool jvalid = jq < JQN;
                const int j0 = jvalid ? jq * 4 : 0;
                const float* __restrict__ dbase = side ? deltaR : deltaL;
                const float* __restrict__ mbase = side ? muR : muL;

                int qs[8];
                const float* lrow[8];
#pragma unroll
                for (int i = 0; i < 8; ++i) {
                    int q = qperm[oct * 8 + i];
                    qs[i] = q;
                    int qq = __builtin_amdgcn_readfirstlane(q < 0 ? 0 : q);
                    lrow[i] = latQ + (size_t)qq * CC;
                }
                float acc[4][8];
#pragma unroll
                for (int u = 0; u < 4; ++u)
#pragma unroll
                    for (int i = 0; i < 8; ++i) acc[u][i] = 0.f;

                const float* __restrict__ dr = dbase + (size_t)j0 * CC;
                for (int k = 0; k < CC; k += 4) {
                    float4 d0 = *reinterpret_cast<const float4*>(dr + 0 * CC + k);
                    float4 d1 = *reinterpret_cast<const float4*>(dr + 1 * CC + k);
                    float4 d2 = *reinterpret_cast<const float4*>(dr + 2 * CC + k);
                    float4 d3 = *reinterpret_cast<const float4*>(dr + 3 * CC + k);
#pragma unroll
                    for (int i = 0; i < 8; ++i) {
                        float4 lv = *reinterpret_cast<const float4*>(lrow[i] + k);
                        acc[0][i] = fmaf(d0.x, lv.x, fmaf(d0.y, lv.y, fmaf(d0.z, lv.z, fmaf(d0.w, lv.w, acc[0][i]))));
                        acc[1][i] = fmaf(d1.x, lv.x, fmaf(d1.y, lv.y, fmaf(d1.z, lv.z, fmaf(d1.w, lv.w, acc[1][i]))));
                        acc[2][i] = fmaf(d2.x, lv.x, fmaf(d2.y, lv.y, fmaf(d2.z, lv.z, fmaf(d2.w, lv.w, acc[2][i]))));
                        acc[3][i] = fmaf(d3.x, lv.x, fmaf(d3.y, lv.y, fmaf(d3.z, lv.z, fmaf(d3.w, lv.w, acc[3][i]))));
                    }
                }
                if (jvalid) {
                    float4 mv = *reinterpret_cast<const float4*>(mbase + j0);
#pragma unroll
                    for (int i = 0; i < 8; ++i) {
                        if (qs[i] >= 0) {
                            float4 o = make_float4(acc[0][i] + mv.x, acc[1][i] + mv.y,
                                                   acc[2][i] + mv.z, acc[3][i] + mv.w);
                            *reinterpret_cast<float4*>(pts3 + (size_t)qs[i] * JD + j0) = o;
                        }
                    }
                }
            }
        }
    }
    grid_barrier(cnt, 2 * NBLK);

    // ---------------- P2: chamfer. block = (half, dir, b). cols split across waves. ----------------
    {
        const int b    = bid & 63;
        const int dir  = (bid >> 6) & 1;
        const int half = bid >> 7;
        const int qa = dir * BB + b;
        const int qb = (1 - dir) * BB + b;
        const float* __restrict__ A3 = pts3 + (size_t)qa * JD + (size_t)half * HALFR * 3;
        const float* __restrict__ B3 = pts3 + (size_t)qb * JD;

        for (int n = tid; n < 1456; n += TPB) {
            float x = 0.f, y = 0.f, z = 0.f, w = 1e30f;
            if (n < NV) {
                x = B3[3 * n]; y = B3[3 * n + 1]; z = B3[3 * n + 2];
                w = fmaf(x, x, fmaf(y, y, z * z));
            }
            sm.u.c.Bx[n] = -2.f * x; sm.u.c.By[n] = -2.f * y;
            sm.u.c.Bz[n] = -2.f * z; sm.u.c.Bw[n] = w;
        }
        __syncthreads();

        const int wv = tid >> 6, lane = tid & 63;
        float ax[12], ay[12], az[12], aw[12], mn[12];
#pragma unroll
        for (int r = 0; r < 12; ++r) {
            int row = lane + 64 * r;
            bool v = row < HALFR;
            float x = v ? A3[3 * row]     : 0.f;
            float y = v ? A3[3 * row + 1] : 0.f;
            float z = v ? A3[3 * row + 2] : 0.f;
            ax[r] = x; ay[r] = y; az[r] = z;
            aw[r] = fmaf(x, x, fmaf(y, y, z * z));
            mn[r] = 1e30f;
        }

        const float4* __restrict__ Bx4 = reinterpret_cast<const float4*>(sm.u.c.Bx);
        const float4* __restrict__ By4 = reinterpret_cast<const float4*>(sm.u.c.By);
        const float4* __restrict__ Bz4 = reinterpret_cast<const float4*>(sm.u.c.Bz);
        const float4* __restrict__ Bw4 = reinterpret_cast<const float4*>(sm.u.c.Bw);
        const int c4lo = wv * 91, c4hi = c4lo + 91;   // 4*364 = 1456 cols incl pad
        for (int c4 = c4lo; c4 < c4hi; ++c4) {
            float4 bx = Bx4[c4], by = By4[c4], bz = Bz4[c4], bw = Bw4[c4];
#pragma unroll
            for (int r = 0; r < 12; ++r) {
                float da = fmaf(bx.x, ax[r], fmaf(by.x, ay[r], fmaf(bz.x, az[r], bw.x)));
                float db = fmaf(bx.y, ax[r], fmaf(by.y, ay[r], fmaf(bz.y, az[r], bw.y)));
                mn[r] = fminf(fminf(mn[r], da), db);           // v_min3_f32
                float dc = fmaf(bx.z, ax[r], fmaf(by.z, ay[r], fmaf(bz.z, az[r], bw.z)));
                float dd = fmaf(bx.w, ax[r], fmaf(by.w, ay[r], fmaf(bz.w, az[r], bw.w)));
                mn[r] = fminf(fminf(mn[r], dc), dd);
            }
        }

#pragma unroll
        for (int r = 0; r < 12; ++r) {
            int row = lane + 64 * r;
            if (row < HALFR) sm.u.c.Lmin[wv][row] = mn[r] + aw[r];
        }
        __syncthreads();

        float s = 0.f;
        for (int i = tid; i < HALFR; i += TPB) {
            float v = fminf(fminf(sm.u.c.Lmin[0][i], sm.u.c.Lmin[1][i]),
                            fminf(sm.u.c.Lmin[2][i], sm.u.c.Lmin[3][i]));
            s += sqrtf(fmaxf(v, 1e-12f));
        }
        s += __shfl_xor(s, 1);
        s += __shfl_xor(s, 2);
        s += __shfl_xor(s, 4);
        s += __shfl_xor(s, 8);
        s += __shfl_xor(s, 16);
        s += __shfl_xor(s, 32);
        if ((tid & 63) == 0) sm.wred[tid >> 6] = s;
        __syncthreads();
        if (tid == 0)
            partials[bid] = (sm.wred[0] + sm.wred[1]) + (sm.wred[2] + sm.wred[3]);
    }
    grid_barrier(cnt, 3 * NBLK);

    // ---------------- P3: final deterministic reduce (block 0, wave 0) ----------------
    if (bid == 0 && tid < 64) {
        float s = ((partials[tid] + partials[tid + 64]) + partials[tid + 128]) + partials[tid + 192];
        s += __shfl_xor(s, 1);
        s += __shfl_xor(s, 2);
        s += __shfl_xor(s, 4);
        s += __shfl_xor(s, 8);
        s += __shfl_xor(s, 16);
        s += __shfl_xor(s, 32);
        if (tid == 0) out[0] = s * (1.0f / (64.0f * 1448.0f));
    }
}

extern "C" void kernel_launch(void* const* d_in, const int* in_sizes, int n_in,
                              void* d_out, int out_size, void* d_ws, size_t ws_size,
                              hipStream_t stream) {
    const float* inp    = (const float*)d_in[0];
    const float* tgt    = (const float*)d_in[1];
    const int*   labels = (const int*)d_in[2];
    const float* muL    = (const float*)d_in[3];
    const float* deltaL = (const float*)d_in[4];
    const float* muR    = (const float*)d_in[5];
    const float* deltaR = (const float*)d_in[6];
    float* out = (float*)d_out;

    char* ws = (char*)d_ws;
    unsigned* cnt    = (unsigned*)ws;                         // 4 B (memset each call)
    float* latQ      = (float*)(ws + 256);                    // 128*256*4 = 131072 B
    int*   qperm     = (int*)(ws + 256 + 131072);             // 144*4
    int*   octside   = (int*)(ws + 256 + 131072 + 1024);      // 18*4
    float* pts3      = (float*)(ws + 256 + 131072 + 2048);    // 128*4344*4 = 2224128 B
    float* partials  = (float*)(ws + 256 + 131072 + 2048 + 2224128); // 256*4

    hipMemsetAsync(cnt, 0, 4, stream);
    hipLaunchKernelGGL(fused_kernel, dim3(NBLK), dim3(TPB), 0, stream,
                       inp, tgt, labels, muL, deltaL, muR, deltaR,
                       cnt, latQ, qperm, octside, pts3, partials, out);
}

// Round 8
// 83.912 us; speedup vs baseline: 10.2937x; 10.2937x over previous
//
#include <hip/hip_runtime.h>

#define NV 1448
#define JD 4344    // 3*NV
#define CC 256
#define BB 64
#define QQ 128     // 2*BB
#define HALFR 724  // rows per chamfer block

// ---------------------------------------------------------------------------
// K1: global average pool over H*W=64 -> latT[c][q], q = t*64+b
// ---------------------------------------------------------------------------
__global__ __launch_bounds__(256) void pool_kernel(const float* __restrict__ inp,
                                                   const float* __restrict__ tgt,
                                                   float* __restrict__ latT) {
    int gid  = blockIdx.x * 256 + threadIdx.x;
    int lane = gid & 15;
    int row  = gid >> 4;
    if (row >= 2 * BB * CC) return;
    int t  = row >> 14;
    int bc = row & 16383;
    const float* src = (t ? tgt : inp) + (size_t)bc * 64;
    float4 v = reinterpret_cast<const float4*>(src)[lane];
    float s = (v.x + v.y) + (v.z + v.w);
    s += __shfl_xor(s, 1);
    s += __shfl_xor(s, 2);
    s += __shfl_xor(s, 4);
    s += __shfl_xor(s, 8);
    if (lane == 0) {
        int b = bc >> 8, c = bc & 255;
        latT[c * QQ + t * BB + b] = s * (1.0f / 64.0f);
    }
}

// ---------------------------------------------------------------------------
// K2: decode GEMM (R5/R6 version, unchanged), 4j x 4q register blocking.
// ---------------------------------------------------------------------------
__global__ __launch_bounds__(256) void decode_kernel(const float* __restrict__ latT,
                                                     const float* __restrict__ muL,
                                                     const float* __restrict__ deltaL,
                                                     const float* __restrict__ muR,
                                                     const float* __restrict__ deltaR,
                                                     const int* __restrict__ labels,
                                                     float* __restrict__ pts3) {
    const int jt = blockIdx.x;                 // 68 tiles of 64 j
    const int L  = blockIdx.y;
    const int qh = blockIdx.z;                 // q half: 64 q's
    const float* __restrict__ delta = L ? deltaR : deltaL;
    const float* __restrict__ mu    = L ? muR : muL;
    const int j0  = jt * 64;
    const int tid = threadIdx.x;
    const int jl  = tid & 15;
    const int qg  = tid >> 4;                  // 0..15

    __shared__ float AsT[32][64];              // [k][j]
    __shared__ float Bs[32][64];               // [k][q]

    float acc[4][4];
#pragma unroll
    for (int u = 0; u < 4; ++u)
#pragma unroll
        for (int v = 0; v < 4; ++v) acc[u][v] = 0.f;

    const int sj = tid & 63;                   // stage: j-lane
    const int sk = (tid >> 6) * 8;             // stage: k-base (0,8,16,24)
    const float4* latT4 = reinterpret_cast<const float4*>(latT);

    for (int kc = 0; kc < CC; kc += 32) {
        __syncthreads();
        {   // stage AsT: 64 j x 32 k
            int j = j0 + sj;
            float4 v0 = make_float4(0.f, 0.f, 0.f, 0.f), v1 = v0;
            if (j < JD) {
                const float4* dp = reinterpret_cast<const float4*>(delta + (size_t)j * CC + kc + sk);
                v0 = dp[0]; v1 = dp[1];
            }
            AsT[sk + 0][sj] = v0.x; AsT[sk + 1][sj] = v0.y;
            AsT[sk + 2][sj] = v0.z; AsT[sk + 3][sj] = v0.w;
            AsT[sk + 4][sj] = v1.x; AsT[sk + 5][sj] = v1.y;
            AsT[sk + 6][sj] = v1.z; AsT[sk + 7][sj] = v1.w;
        }
        {   // stage Bs: 32 k x 64 q = 512 float4, 2 per thread
            int k  = tid >> 4;                 // 0..15
            int qi = tid & 15;
            reinterpret_cast<float4*>(&Bs[k][0])[qi]      = latT4[(size_t)(kc + k) * 32 + qh * 16 + qi];
            reinterpret_cast<float4*>(&Bs[k + 16][0])[qi] = latT4[(size_t)(kc + k + 16) * 32 + qh * 16 + qi];
        }
        __syncthreads();

#pragma unroll
        for (int k4 = 0; k4 < 32; k4 += 4) {
#pragma unroll
            for (int kk = 0; kk < 4; ++kk) {
                float4 a = *reinterpret_cast<const float4*>(&AsT[k4 + kk][jl * 4]);
                float4 b = *reinterpret_cast<const float4*>(&Bs[k4 + kk][qg * 4]);
                float av[4] = {a.x, a.y, a.z, a.w};
                float bv[4] = {b.x, b.y, b.z, b.w};
#pragma unroll
                for (int u = 0; u < 4; ++u)
#pragma unroll
                    for (int v = 0; v < 4; ++v)
                        acc[u][v] = fmaf(av[u], bv[v], acc[u][v]);
            }
        }
    }

    int j = j0 + jl * 4;
    if (j < JD) {
        float4 m = *reinterpret_cast<const float4*>(mu + j);
        float mu4[4] = {m.x, m.y, m.z, m.w};
#pragma unroll
        for (int v = 0; v < 4; ++v) {
            int q = qh * 64 + qg * 4 + v;
            int b = q & 63;
            if (labels[b] == L) {
                float4 o = make_float4(acc[0][v] + mu4[0], acc[1][v] + mu4[1],
                                       acc[2][v] + mu4[2], acc[3][v] + mu4[3]);
                *reinterpret_cast<float4*>(pts3 + (size_t)q * JD + j) = o;
            }
        }
    }
}

// ---------------------------------------------------------------------------
// K2b: pack points as float4(x,y,z,|p|^2)  (raw, unscaled)
// ---------------------------------------------------------------------------
__global__ __launch_bounds__(256) void pack_kernel(const float* __restrict__ pts3,
                                                   float4* __restrict__ pts4) {
    int gid = blockIdx.x * 256 + threadIdx.x;   // QQ*NV = 185344 = 724*256
    if (gid >= QQ * NV) return;
    int tb = gid / NV;
    int n  = gid - tb * NV;
    const float* p = pts3 + (size_t)tb * JD + n * 3;
    float x = p[0], y = p[1], z = p[2];
    pts4[gid] = make_float4(x, y, z, fmaf(x, x, fmaf(y, y, z * z)));
}

// ---------------------------------------------------------------------------
// K3: chamfer, NO LDS. B columns are wave-uniform float4 loads straight from
// pts4 (scalar/L1-broadcast path, NOT the LDS pipe), 2-col register prefetch.
// Each block: 724 rows (3/thread, in regs, pre-scaled -2) x ALL 1448 cols ->
// final row-min -> sqrt -> block sum -> partials. No combine pass needed.
// grid (b, dir, half) = 256 blocks x 256 thr.
// ---------------------------------------------------------------------------
__global__ __launch_bounds__(256, 1) void chamfer_kernel(const float4* __restrict__ pts4,
                                                         float* __restrict__ partials) {
    const int b    = blockIdx.x;
    const int dir  = blockIdx.y;
    const int half = blockIdx.z;
    const int qa = dir * BB + b;
    const int qb = (1 - dir) * BB + b;
    const float4* __restrict__ Ap = pts4 + (size_t)qa * NV + half * HALFR;
    const float4* __restrict__ Bp = pts4 + (size_t)qb * NV;
    const int tid = threadIdx.x;

    float Ax[3], Ay[3], Az[3], Aw[3], mn[3];
#pragma unroll
    for (int r = 0; r < 3; ++r) {
        int row = tid + 256 * r;
        float4 a = Ap[row < HALFR ? row : 0];
        Ax[r] = -2.f * a.x; Ay[r] = -2.f * a.y; Az[r] = -2.f * a.z;
        Aw[r] = a.w;
        mn[r] = 1e30f;
    }

    float4 b0 = Bp[0], b1 = Bp[1];
    for (int m = 0; m < NV; m += 2) {
        float4 n0 = Bp[m + 2];   // slack-padded buffer: safe overread, discarded
        float4 n1 = Bp[m + 3];
#pragma unroll
        for (int r = 0; r < 3; ++r) {
            float d0 = fmaf(Ax[r], b0.x, fmaf(Ay[r], b0.y, fmaf(Az[r], b0.z, b0.w)));
            float d1 = fmaf(Ax[r], b1.x, fmaf(Ay[r], b1.y, fmaf(Az[r], b1.z, b1.w)));
            mn[r] = fminf(fminf(mn[r], d0), d1);   // v_min3_f32
        }
        b0 = n0; b1 = n1;
    }

    float s = 0.f;
#pragma unroll
    for (int r = 0; r < 3; ++r) {
        int row = tid + 256 * r;
        if (row < HALFR) s += sqrtf(fmaxf(mn[r] + Aw[r], 1e-12f));
    }
    s += __shfl_xor(s, 1);
    s += __shfl_xor(s, 2);
    s += __shfl_xor(s, 4);
    s += __shfl_xor(s, 8);
    s += __shfl_xor(s, 16);
    s += __shfl_xor(s, 32);
    __shared__ float wsum[4];
    if ((tid & 63) == 0) wsum[tid >> 6] = s;
    __syncthreads();
    if (tid == 0)
        partials[(blockIdx.z * 2 + blockIdx.y) * 64 + blockIdx.x] =
            (wsum[0] + wsum[1]) + (wsum[2] + wsum[3]);
}

// ---------------------------------------------------------------------------
// K4: final reduce of 256 partials -> scalar (single block, deterministic)
// ---------------------------------------------------------------------------
__global__ __launch_bounds__(256) void finalize_kernel(const float* __restrict__ partials,
                                                       float* __restrict__ out) {
    int tid = threadIdx.x;
    float s = partials[tid];
    s += __shfl_xor(s, 1);
    s += __shfl_xor(s, 2);
    s += __shfl_xor(s, 4);
    s += __shfl_xor(s, 8);
    s += __shfl_xor(s, 16);
    s += __shfl_xor(s, 32);
    __shared__ float wsum[4];
    if ((tid & 63) == 0) wsum[tid >> 6] = s;
    __syncthreads();
    if (tid == 0)
        out[0] = ((wsum[0] + wsum[1]) + (wsum[2] + wsum[3])) * (1.0f / (64.0f * 1448.0f));
}

extern "C" void kernel_launch(void* const* d_in, const int* in_sizes, int n_in,
                              void* d_out, int out_size, void* d_ws, size_t ws_size,
                              hipStream_t stream) {
    const float* inp    = (const float*)d_in[0];
    const float* tgt    = (const float*)d_in[1];
    const int*   labels = (const int*)d_in[2];
    const float* muL    = (const float*)d_in[3];
    const float* deltaL = (const float*)d_in[4];
    const float* muR    = (const float*)d_in[5];
    const float* deltaR = (const float*)d_in[6];
    float* out = (float*)d_out;

    char* ws = (char*)d_ws;
    float*  latT     = (float*)ws;                               // 256*128*4 = 128 KB
    float*  pts3     = (float*)(ws + (128 << 10));               // 128*4344*4 = 2224128 B
    float4* pts4     = (float4*)(ws + (128 << 10) + 2224128);    // 185344*16 + slack
    float*  partials = (float*)((char*)pts4 + ((size_t)QQ * NV + 8) * sizeof(float4)); // 256*4

    hipLaunchKernelGGL(pool_kernel, dim3(2048), dim3(256), 0, stream, inp, tgt, latT);
    hipLaunchKernelGGL(decode_kernel, dim3(68, 2, 2), dim3(256), 0, stream,
                       latT, muL, deltaL, muR, deltaR, labels, pts3);
    hipLaunchKernelGGL(pack_kernel, dim3((QQ * NV + 255) / 256), dim3(256), 0, stream,
                       pts3, pts4);
    hipLaunchKernelGGL(chamfer_kernel, dim3(64, 2, 2), dim3(256), 0, stream,
                       pts4, partials);
    hipLaunchKernelGGL(finalize_kernel, dim3(1), dim3(256), 0, stream, partials, out);
}